// Round 23
// baseline (198.328 us; speedup 1.0000x reference)
//
#include <hip/hip_runtime.h>
#include <stdint.h>

#define B 8
#define N 460800
#define NV4 115200          // N/4 float4 scores per image
#define PRE 2000
#define POST 1000
#define CAP 4096
#define NBIN 4096
#define RANKP 2048
#define NWORD 32
#define NMS_T 0.7f
#define XCLIP 4.135166556742356

#define SCAN_BLOCKS 45      // 45*256*10 = 115200
#define SCAN_ITER 10
#define SCAN_STRIDE (SCAN_BLOCKS * 256)
#define NTRI (NWORD * (NWORD + 1) / 2)   // 528

typedef unsigned long long u64;

__device__ __forceinline__ uint32_t fkey(float f) {
    uint32_t u = __float_as_uint(f);
    return (u & 0x80000000u) ? ~u : (u | 0x80000000u);
}

__device__ __forceinline__ u64 readlane_u64(u64 v, int lane) {
    uint32_t lo = __builtin_amdgcn_readlane((uint32_t)v, lane);
    uint32_t hi = __builtin_amdgcn_readlane((uint32_t)(v >> 32), lane);
    return ((u64)hi << 32) | lo;
}

// ---------------- Stage 0: zero hist+cnt+done ----------------
#define ZBYTES 131360                     // hist (131072) + cnt (256) + done (32)
__global__ __launch_bounds__(256) void k_zero(uint4* __restrict__ p) {
    int i = blockIdx.x * 256 + threadIdx.x;
    if (i < ZBYTES / 16) p[i] = make_uint4(0u, 0u, 0u, 0u);
}

// ---------------- Stage 1: per-image histogram of score keys (top 12 bits) ----------------
__global__ __launch_bounds__(256) void k_hist(const float4* __restrict__ obj4,
                                              uint32_t* __restrict__ hist) {
    __shared__ uint32_t lh[2][NBIN];   // 32 KiB, 2-way replicated to cut contention
    int b = blockIdx.y;
    for (int i = threadIdx.x; i < NBIN; i += 256) { lh[0][i] = 0; lh[1][i] = 0; }
    __syncthreads();
    const float4* s = obj4 + (size_t)b * NV4;
    int t0 = blockIdx.x * 256 + threadIdx.x;
    uint32_t* h = lh[threadIdx.x & 1];
    float4 v[SCAN_ITER];
#pragma unroll
    for (int k = 0; k < SCAN_ITER; ++k) v[k] = s[t0 + k * SCAN_STRIDE];
#pragma unroll
    for (int k = 0; k < SCAN_ITER; ++k) {
        atomicAdd(&h[fkey(v[k].x) >> 20], 1u);
        atomicAdd(&h[fkey(v[k].y) >> 20], 1u);
        atomicAdd(&h[fkey(v[k].z) >> 20], 1u);
        atomicAdd(&h[fkey(v[k].w) >> 20], 1u);
    }
    __syncthreads();
    uint32_t* gh = hist + (size_t)b * NBIN;
    for (int i = threadIdx.x; i < NBIN; i += 256) {
        uint32_t s2 = lh[0][i] + lh[1][i];
        if (s2) atomicAdd(&gh[i], s2);
    }
}

// ---------------- Stage 2+3 fused: wave 0 computes cutoff bin, then compact ------------
#define LBUF 2048
__global__ __launch_bounds__(256) void k_compact(const float4* __restrict__ obj4,
                                                 const uint32_t* __restrict__ hist,
                                                 uint32_t* __restrict__ cnt,
                                                 u64* __restrict__ cand) {
    __shared__ u64 buf[LBUF];          // 16 KiB
    __shared__ uint32_t lcnt, base, cutsh;
    int b = blockIdx.y;
    if (threadIdx.x == 0) lcnt = 0;
    if (threadIdx.x < 64) {
        int lane = threadIdx.x;
        const uint32_t* h = hist + (size_t)b * NBIN;
        uint32_t gs = 0;
        for (int t = 0; t < 64; ++t) gs += h[lane * 64 + t];
        uint32_t suf = gs;
        for (int d = 1; d < 64; d <<= 1) {
            uint32_t vv = __shfl_down(suf, d);
            if (lane + d < 64) suf += vv;
        }
        unsigned long long m = __ballot(suf >= PRE);
        int G = 63 - __clzll(m);
        uint32_t A = 0;
        if (G < 63) A = __shfl(suf, G + 1);
        uint32_t hv = h[G * 64 + lane];
        uint32_t suf2 = hv;
        for (int d = 1; d < 64; d <<= 1) {
            uint32_t vv = __shfl_down(suf2, d);
            if (lane + d < 64) suf2 += vv;
        }
        unsigned long long m2 = __ballot(A + suf2 >= PRE);
        int t2 = 63 - __clzll(m2);
        if (lane == 0) cutsh = (uint32_t)(G * 64 + t2);
    }
    __syncthreads();
    uint32_t cb = cutsh;
    const float4* s = obj4 + (size_t)b * NV4;
    int t0 = blockIdx.x * 256 + threadIdx.x;
    float4 v[SCAN_ITER];
#pragma unroll
    for (int k = 0; k < SCAN_ITER; ++k) v[k] = s[t0 + k * SCAN_STRIDE];
#pragma unroll
    for (int k = 0; k < SCAN_ITER; ++k) {
        int i4 = (t0 + k * SCAN_STRIDE) * 4;
        float fv[4] = {v[k].x, v[k].y, v[k].z, v[k].w};
#pragma unroll
        for (int c = 0; c < 4; ++c) {
            uint32_t key = fkey(fv[c]);
            if ((key >> 20) >= cb) {
                uint32_t p = atomicAdd(&lcnt, 1u);
                u64 e = ((u64)key << 32) | (uint32_t)(~(uint32_t)(i4 + c));
                if (p < LBUF) buf[p] = e;
                else {
                    uint32_t g = atomicAdd(&cnt[b], 1u);
                    if (g < CAP) cand[(size_t)b * CAP + g] = e;
                }
            }
        }
    }
    __syncthreads();
    uint32_t nb = lcnt < LBUF ? lcnt : LBUF;
    if (threadIdx.x == 0) base = atomicAdd(&cnt[b], nb);
    __syncthreads();
    uint32_t bs = base;
    for (uint32_t t = threadIdx.x; t < nb; t += 256) {
        uint32_t g = bs + t;
        if (g < CAP) cand[(size_t)b * CAP + g] = buf[t];
    }
}

// ---------------- Stage 4+5: counting-rank (2-wave split) + decode + occ-zero ----------------
// 128 threads: wave 0 scans j-groups [0,ng/2), wave 1 [ng/2,ng); partial ranks combined
// via LDS; wave 0 decodes + scatters + zeroes occ[rank] (bijective over [0,RANKP)).
__global__ __launch_bounds__(128) void k_rankdec(const uint32_t* __restrict__ cnt,
                                                 const u64* __restrict__ cand,
                                                 const float4* __restrict__ anchors,
                                                 const float4* __restrict__ deltas,
                                                 float4* __restrict__ boxes,
                                                 uint32_t* __restrict__ occ) {
    __shared__ uint32_t rpart[64];
    int b = blockIdx.x;
    int tid = threadIdx.x;
    int wid = tid >> 6, lane = tid & 63;
    int slot = blockIdx.y * 64 + lane;            // 0..4095
    uint32_t n = cnt[b]; if (n > CAP) n = CAP;
    const u64* C = cand + (size_t)b * CAP;
    u64 mykey = (slot < (int)n) ? C[slot] : 0ull;
    int r = 0;
    bool allpad = (blockIdx.y * 64 >= (int)n);    // whole block is pad rows
    if (!allpad) {
        int ng = ((int)n + 63) >> 6;
        int g0 = wid ? (ng >> 1) : 0;
        int g1 = wid ? ng : (ng >> 1);
        auto ld = [&](int g) -> u64 {
            int j = g * 64 + lane;
            int jc = j < (CAP - 1) ? j : (CAP - 1);
            u64 kv = C[jc];
            return (j < (int)n) ? kv : 0ull;      // 0 never counts (real keys have MSB set)
        };
        u64 kv0 = ld(g0), kv1 = ld(g0 + 1), kv2 = ld(g0 + 2);
        int r0 = 0, r1 = 0;
        for (int g = g0; g < g1; ++g) {
            u64 kvn = ld(g + 3);
#pragma unroll
            for (int t = 0; t < 64; t += 2) {
                u64 ka = readlane_u64(kv0, t);
                u64 kb = readlane_u64(kv0, t + 1);
                r0 += (ka > mykey) ? 1 : 0;
                r1 += (kb > mykey) ? 1 : 0;
            }
            kv0 = kv1; kv1 = kv2; kv2 = kvn;
        }
        r = r0 + r1;
    }
    if (wid == 1) rpart[lane] = (uint32_t)r;
    __syncthreads();
    if (wid == 0) {
        r += (int)rpart[lane];
        int rank = (slot < (int)n) ? r : slot;    // pads cover rows [n,2048) bijectively
        if (rank < RANKP) {
            float4 outb = make_float4(0.f, 0.f, 0.f, 0.f);
            if (slot < (int)n && rank < PRE) {
                uint32_t idx = ~(uint32_t)mykey;
                if (idx < N) {
                    float4 a = anchors[idx];
                    float4 d = deltas[(size_t)b * N + idx];
                    float w = a.z - a.x, h = a.w - a.y;
                    float cx = a.x + 0.5f * w, cy = a.y + 0.5f * h;
                    float dw = fminf(d.z, (float)XCLIP);
                    float dh = fminf(d.w, (float)XCLIP);
                    float pcx = d.x * w + cx, pcy = d.y * h + cy;
                    float pw = expf(dw) * w, ph = expf(dh) * h;
                    float x1 = pcx - 0.5f * pw, y1 = pcy - 0.5f * ph;
                    float x2 = pcx + 0.5f * pw, y2 = pcy + 0.5f * ph;
                    x1 = fminf(fmaxf(x1, 0.f), 1024.f);
                    y1 = fminf(fmaxf(y1, 0.f), 1024.f);
                    x2 = fminf(fmaxf(x2, 0.f), 1024.f);
                    y2 = fminf(fmaxf(y2, 0.f), 1024.f);
                    outb = make_float4(x1, y1, x2, y2);
                }
            }
            boxes[(size_t)b * RANKP + rank] = outb;
            occ[(size_t)b * RANKP + rank] = 0u;   // zero exactly once per row
        }
    }
}

// ---------------- Stage 6: adjacency + occupancy + valid, then LAST BLOCK runs NMS ----------------
// adj[i][w] bit k: IoU(i, 64w+k) > T AND 64w+k < i (lower triangle; IoU numerically
// symmetric = exact transpose of suppression). occ[i] bit w iff adj[i][w]!=0.
// After each block's stores: __threadfence(); atomicAdd(done[b]) — the block observing
// old==NTRI-1 acquires (fence) and runs the sparse NMS + stable-partition output for
// image b. No dispatch-order assumption; done[] zeroed by k_zero each call.
__global__ __launch_bounds__(64) void k_masknms(const float4* __restrict__ boxes,
                                                u64* __restrict__ adj,
                                                uint32_t* __restrict__ occ,
                                                u64* __restrict__ valid,
                                                uint32_t* __restrict__ done,
                                                float4* __restrict__ out) {
    int b = blockIdx.x;
    int L = blockIdx.y;
    int tw = 0, rem = L;
    while (rem >= NWORD - tw) { rem -= NWORD - tw; ++tw; }
    int tr = tw + rem;                   // tw <= tr: columns = earlier tile, rows = later
    __shared__ float4 jb[64];
    __shared__ float ja[64];
    __shared__ uint32_t oldv;
    int lane = threadIdx.x;  // 64 threads
    const float4* bx = boxes + (size_t)b * RANKP;
    float4 v = bx[tw * 64 + lane];
    jb[lane] = v;
    ja[lane] = (v.z - v.x) * (v.w - v.y);
    int i = tr * 64 + lane;              // this lane's row (later box)
    float4 bi = bx[i];
    float ai = (bi.z - bi.x) * (bi.w - bi.y);
    __syncthreads();
    u64 word = 0;
    for (int kk = 0; kk < 64; ++kk) {
        int j = tw * 64 + kk;
        float4 bj = jb[kk];
        float xx1 = fmaxf(bi.x, bj.x), yy1 = fmaxf(bi.y, bj.y);
        float xx2 = fminf(bi.z, bj.z), yy2 = fminf(bi.w, bj.w);
        float iw = fmaxf(xx2 - xx1, 0.f), ih = fmaxf(yy2 - yy1, 0.f);
        float inter = iw * ih;
        float iou = inter / (ai + ja[kk] - inter);   // NaN -> compare false
        if (j < i && iou > NMS_T) word |= 1ull << kk;
    }
    adj[((size_t)b * RANKP + i) * NWORD + tw] = word;
    if (word) atomicOr(&occ[(size_t)b * RANKP + i], 1u << tw);
    if (tw == tr) {
        bool ok = !((bi.z - bi.x < 1e-3f) || (bi.w - bi.y < 1e-3f));
        u64 bal = __ballot(ok);
        if (lane == 0) valid[(size_t)b * NWORD + tr] = bal;
    }
    // ---- last-block election ----
    __threadfence();                     // release this block's adj/occ/valid stores
    if (lane == 0) oldv = atomicAdd(&done[b], 1u);
    __syncthreads();
    if (oldv != NTRI - 1) return;
    __threadfence();                     // acquire all other blocks' stores
    // ======== NMS phase (winner block only; body identical to proven r21 k_nms) ========
    const u64* AdjG = adj + (size_t)b * RANKP * NWORD;
    const uint32_t* OccG = occ + (size_t)b * RANKP;
    uint32_t o[NWORD];
#pragma unroll
    for (int g = 0; g < NWORD; ++g) o[g] = OccG[g * 64 + lane];
    u64 vw = (lane < 32) ? valid[(size_t)b * NWORD + lane] : 0ull;
    u64 t1[NWORD];
#pragma unroll
    for (int g = 0; g < NWORD; ++g) {
        uint32_t m = o[g];
        int w1 = m ? (int)__builtin_ctz(m) : 0;
        t1[g] = AdjG[(size_t)(g * 64 + lane) * NWORD + w1];
    }
    u64 kw = vw;
    int kcnt = 0;
    bool fin = false;
#pragma unroll
    for (int c = 0; c < NWORD; ++c) {
        if (!fin) {
            u64 om = __ballot(o[c] != 0);
            u64 vmask = readlane_u64(vw, c);
            u64 kc;
            if (om == 0ull) {
                kc = vmask;
            } else {
                kc = vmask & ~om;
                u64 mm = om;
                while (mm) {
                    int ii = (int)__builtin_ctzll(mm); mm &= mm - 1;
                    uint32_t occv = __builtin_amdgcn_readlane(o[c], ii);
                    bool suppressed = false;
                    uint32_t m2 = occv;
                    int w = (int)__builtin_ctz(m2); m2 &= m2 - 1;
                    u64 arow = readlane_u64(t1[c], ii);
                    u64 ks = (w == c) ? kc : readlane_u64(kw, w);
                    if (arow & ks) suppressed = true;
                    while (m2 && !suppressed) {
                        w = (int)__builtin_ctz(m2); m2 &= m2 - 1;
                        u64 a2 = AdjG[(size_t)(c * 64 + ii) * NWORD + w];
                        ks = (w == c) ? kc : readlane_u64(kw, w);
                        if (a2 & ks) suppressed = true;
                    }
                    if (((vmask >> ii) & 1ull) && !suppressed) kc |= 1ull << ii;
                }
            }
            if (lane == c) kw = kc;
            kcnt += (int)__popcll(kc);
            if (kcnt >= POST) fin = true;
        }
    }
    int tot = 0;
    for (int ww = 0; ww < NWORD; ++ww)
        tot += (int)__popcll(readlane_u64(kw, ww));
    u64 below = (1ull << lane) - 1ull;
    int kcum = 0, ucum = 0;
    for (int ww = 0; ww < NWORD; ++ww) {
        u64 kv = readlane_u64(kw, ww);
        int pc = (int)__popcll(kv);
        bool kp = (kv >> lane) & 1ull;
        int pos;
        if (kp) pos = kcum + (int)__popcll(kv & below);
        else    pos = tot + ucum + (int)__popcll((~kv) & below);
        if (pos < POST) out[(size_t)b * POST + pos] = boxes[(size_t)b * RANKP + ww * 64 + lane];
        kcum += pc;
        ucum += 64 - pc;
    }
}

extern "C" void kernel_launch(void* const* d_in, const int* in_sizes, int n_in,
                              void* d_out, int out_size, void* d_ws, size_t ws_size,
                              hipStream_t stream) {
    const float* anchors = (const float*)d_in[0];   // [N,4]
    const float* obj     = (const float*)d_in[1];   // [B,N]
    const float* deltas  = (const float*)d_in[2];   // [B,N,4]
    char* ws = (char*)d_ws;

    uint32_t* hist   = (uint32_t*)(ws + 0);        // 131072 (zeroed by k_zero)
    uint32_t* cnt    = (uint32_t*)(ws + 131072);   // 256    (zeroed by k_zero)
    uint32_t* done   = (uint32_t*)(ws + 131328);   // 32     (zeroed by k_zero)
    uint32_t* occ    = (uint32_t*)(ws + 131584);   // 65536  (zeroed by k_rankdec) -> 197120
    u64*      cand   = (u64*)(ws + 197120);        // 262144 -> 459264
    float4*   boxes  = (float4*)(ws + 459264);     // 524288 -> 983552
    u64*      valid  = (u64*)(ws + 983552);        // 2048 -> 985600
    u64*      adj    = (u64*)(ws + 985600);        // 4194304 -> 5179904

    k_zero<<<(ZBYTES / 16 + 255) / 256, 256, 0, stream>>>((uint4*)ws);

    dim3 gscan(SCAN_BLOCKS, B);
    k_hist<<<gscan, 256, 0, stream>>>((const float4*)obj, hist);
    k_compact<<<gscan, 256, 0, stream>>>((const float4*)obj, hist, cnt, cand);
    dim3 grank(B, CAP / 64);
    k_rankdec<<<grank, 128, 0, stream>>>(cnt, cand, (const float4*)anchors,
                                         (const float4*)deltas, boxes, occ);
    dim3 gmask(B, NTRI);
    k_masknms<<<gmask, 64, 0, stream>>>(boxes, adj, occ, valid, done, (float4*)d_out);
}

// Round 24
// 112.007 us; speedup vs baseline: 1.7707x; 1.7707x over previous
//
#include <hip/hip_runtime.h>
#include <stdint.h>

#define B 8
#define N 460800
#define NV4 115200          // N/4 float4 scores per image
#define PRE 2000
#define POST 1000
#define CAP 4096
#define NBIN 4096
#define RANKP 2048
#define NWORD 32
#define NMS_T 0.7f
#define XCLIP 4.135166556742356

#define SCAN_BLOCKS 225     // 225*256*2 = 115200
#define SCAN_ITER 2
#define SCAN_STRIDE (SCAN_BLOCKS * 256)
#define NTRI (NWORD * (NWORD + 1) / 2)   // 528

typedef unsigned long long u64;

__device__ __forceinline__ uint32_t fkey(float f) {
    uint32_t u = __float_as_uint(f);
    return (u & 0x80000000u) ? ~u : (u | 0x80000000u);
}

__device__ __forceinline__ u64 readlane_u64(u64 v, int lane) {
    uint32_t lo = __builtin_amdgcn_readlane((uint32_t)v, lane);
    uint32_t hi = __builtin_amdgcn_readlane((uint32_t)(v >> 32), lane);
    return ((u64)hi << 32) | lo;
}

// ---------------- Stage 0: zero hist+cnt ----------------
#define ZBYTES 131328                     // hist (131072) + cnt (256)
__global__ __launch_bounds__(256) void k_zero(uint4* __restrict__ p) {
    int i = blockIdx.x * 256 + threadIdx.x;
    if (i < ZBYTES / 16) p[i] = make_uint4(0u, 0u, 0u, 0u);
}

// ---------------- Stage 1: per-image histogram of score keys (top 12 bits) ----------------
__global__ __launch_bounds__(256) void k_hist(const float4* __restrict__ obj4,
                                              uint32_t* __restrict__ hist) {
    __shared__ uint32_t lh[2][NBIN];   // 32 KiB, 2-way replicated to cut contention
    int b = blockIdx.y;
    for (int i = threadIdx.x; i < NBIN; i += 256) { lh[0][i] = 0; lh[1][i] = 0; }
    __syncthreads();
    const float4* s = obj4 + (size_t)b * NV4;
    int t0 = blockIdx.x * 256 + threadIdx.x;
    uint32_t* h = lh[threadIdx.x & 1];
    float4 v[SCAN_ITER];
#pragma unroll
    for (int k = 0; k < SCAN_ITER; ++k) v[k] = s[t0 + k * SCAN_STRIDE];
#pragma unroll
    for (int k = 0; k < SCAN_ITER; ++k) {
        atomicAdd(&h[fkey(v[k].x) >> 20], 1u);
        atomicAdd(&h[fkey(v[k].y) >> 20], 1u);
        atomicAdd(&h[fkey(v[k].z) >> 20], 1u);
        atomicAdd(&h[fkey(v[k].w) >> 20], 1u);
    }
    __syncthreads();
    uint32_t* gh = hist + (size_t)b * NBIN;
    for (int i = threadIdx.x; i < NBIN; i += 256) {
        uint32_t s2 = lh[0][i] + lh[1][i];
        if (s2) atomicAdd(&gh[i], s2);
    }
}

// ---------------- Stage 2+3 fused: wave 0 computes cutoff bin, then compact ------------
#define LBUF 2048
__global__ __launch_bounds__(256) void k_compact(const float4* __restrict__ obj4,
                                                 const uint32_t* __restrict__ hist,
                                                 uint32_t* __restrict__ cnt,
                                                 u64* __restrict__ cand) {
    __shared__ u64 buf[LBUF];          // 16 KiB
    __shared__ uint32_t lcnt, base, cutsh;
    int b = blockIdx.y;
    if (threadIdx.x == 0) lcnt = 0;
    if (threadIdx.x < 64) {
        int lane = threadIdx.x;
        const uint32_t* h = hist + (size_t)b * NBIN;
        uint32_t gs = 0;
        for (int t = 0; t < 64; ++t) gs += h[lane * 64 + t];
        uint32_t suf = gs;
        for (int d = 1; d < 64; d <<= 1) {
            uint32_t vv = __shfl_down(suf, d);
            if (lane + d < 64) suf += vv;
        }
        unsigned long long m = __ballot(suf >= PRE);
        int G = 63 - __clzll(m);
        uint32_t A = 0;
        if (G < 63) A = __shfl(suf, G + 1);
        uint32_t hv = h[G * 64 + lane];
        uint32_t suf2 = hv;
        for (int d = 1; d < 64; d <<= 1) {
            uint32_t vv = __shfl_down(suf2, d);
            if (lane + d < 64) suf2 += vv;
        }
        unsigned long long m2 = __ballot(A + suf2 >= PRE);
        int t2 = 63 - __clzll(m2);
        if (lane == 0) cutsh = (uint32_t)(G * 64 + t2);
    }
    __syncthreads();
    uint32_t cb = cutsh;
    const float4* s = obj4 + (size_t)b * NV4;
    int t0 = blockIdx.x * 256 + threadIdx.x;
    float4 v[SCAN_ITER];
#pragma unroll
    for (int k = 0; k < SCAN_ITER; ++k) v[k] = s[t0 + k * SCAN_STRIDE];
#pragma unroll
    for (int k = 0; k < SCAN_ITER; ++k) {
        int i4 = (t0 + k * SCAN_STRIDE) * 4;
        float fv[4] = {v[k].x, v[k].y, v[k].z, v[k].w};
#pragma unroll
        for (int c = 0; c < 4; ++c) {
            uint32_t key = fkey(fv[c]);
            if ((key >> 20) >= cb) {
                uint32_t p = atomicAdd(&lcnt, 1u);
                u64 e = ((u64)key << 32) | (uint32_t)(~(uint32_t)(i4 + c));
                if (p < LBUF) buf[p] = e;
                else {   // unreachable: block covers 2048 scores = LBUF
                    uint32_t g = atomicAdd(&cnt[b], 1u);
                    if (g < CAP) cand[(size_t)b * CAP + g] = e;
                }
            }
        }
    }
    __syncthreads();
    uint32_t nb = lcnt < LBUF ? lcnt : LBUF;
    if (threadIdx.x == 0) base = atomicAdd(&cnt[b], nb);
    __syncthreads();
    uint32_t bs = base;
    for (uint32_t t = threadIdx.x; t < nb; t += 256) {
        uint32_t g = bs + t;
        if (g < CAP) cand[(size_t)b * CAP + g] = buf[t];
    }
}

// ---------------- Stage 4+5: counting-rank (2-wave split) + decode + occ-zero ----------------
// 128 threads: wave 0 scans j-groups [0,ng/2), wave 1 [ng/2,ng); partial ranks combined
// via LDS; wave 0 decodes + scatters + zeroes occ[rank] (bijective over [0,RANKP)).
__global__ __launch_bounds__(128) void k_rankdec(const uint32_t* __restrict__ cnt,
                                                 const u64* __restrict__ cand,
                                                 const float4* __restrict__ anchors,
                                                 const float4* __restrict__ deltas,
                                                 float4* __restrict__ boxes,
                                                 uint32_t* __restrict__ occ) {
    __shared__ uint32_t rpart[64];
    int b = blockIdx.x;
    int tid = threadIdx.x;
    int wid = tid >> 6, lane = tid & 63;
    int slot = blockIdx.y * 64 + lane;            // 0..4095
    uint32_t n = cnt[b]; if (n > CAP) n = CAP;
    const u64* C = cand + (size_t)b * CAP;
    u64 mykey = (slot < (int)n) ? C[slot] : 0ull;
    int r = 0;
    bool allpad = (blockIdx.y * 64 >= (int)n);    // whole block is pad rows
    if (!allpad) {
        int ng = ((int)n + 63) >> 6;
        int g0 = wid ? (ng >> 1) : 0;
        int g1 = wid ? ng : (ng >> 1);
        auto ld = [&](int g) -> u64 {
            int j = g * 64 + lane;
            int jc = j < (CAP - 1) ? j : (CAP - 1);
            u64 kv = C[jc];
            return (j < (int)n) ? kv : 0ull;      // 0 never counts (real keys have MSB set)
        };
        u64 kv0 = ld(g0), kv1 = ld(g0 + 1), kv2 = ld(g0 + 2);
        int r0 = 0, r1 = 0;
        for (int g = g0; g < g1; ++g) {
            u64 kvn = ld(g + 3);
#pragma unroll
            for (int t = 0; t < 64; t += 2) {
                u64 ka = readlane_u64(kv0, t);
                u64 kb = readlane_u64(kv0, t + 1);
                r0 += (ka > mykey) ? 1 : 0;
                r1 += (kb > mykey) ? 1 : 0;
            }
            kv0 = kv1; kv1 = kv2; kv2 = kvn;
        }
        r = r0 + r1;
    }
    if (wid == 1) rpart[lane] = (uint32_t)r;
    __syncthreads();
    if (wid == 0) {
        r += (int)rpart[lane];
        int rank = (slot < (int)n) ? r : slot;    // pads cover rows [n,2048) bijectively
        if (rank < RANKP) {
            float4 outb = make_float4(0.f, 0.f, 0.f, 0.f);
            if (slot < (int)n && rank < PRE) {
                uint32_t idx = ~(uint32_t)mykey;
                if (idx < N) {
                    float4 a = anchors[idx];
                    float4 d = deltas[(size_t)b * N + idx];
                    float w = a.z - a.x, h = a.w - a.y;
                    float cx = a.x + 0.5f * w, cy = a.y + 0.5f * h;
                    float dw = fminf(d.z, (float)XCLIP);
                    float dh = fminf(d.w, (float)XCLIP);
                    float pcx = d.x * w + cx, pcy = d.y * h + cy;
                    float pw = expf(dw) * w, ph = expf(dh) * h;
                    float x1 = pcx - 0.5f * pw, y1 = pcy - 0.5f * ph;
                    float x2 = pcx + 0.5f * pw, y2 = pcy + 0.5f * ph;
                    x1 = fminf(fmaxf(x1, 0.f), 1024.f);
                    y1 = fminf(fmaxf(y1, 0.f), 1024.f);
                    x2 = fminf(fmaxf(x2, 0.f), 1024.f);
                    y2 = fminf(fmaxf(y2, 0.f), 1024.f);
                    outb = make_float4(x1, y1, x2, y2);
                }
            }
            boxes[(size_t)b * RANKP + rank] = outb;
            occ[(size_t)b * RANKP + rank] = 0u;   // zero exactly once per row
        }
    }
}

// ---------------- Stage 6a: ADJACENCY bitmask + occupancy + valid ----------------
// adj[i][w] bit k: IoU(i, 64w+k) > T AND 64w+k < i (lower triangle; IoU numerically
// symmetric = exact transpose of suppression). occ[i] bit w iff adj[i][w]!=0 (rare;
// atomicOr onto k_rankdec-zeroed occ). Only words w <= i/64 WRITTEN; occ guards reads.
__global__ void k_mask(const float4* __restrict__ boxes, u64* __restrict__ adj,
                       uint32_t* __restrict__ occ, u64* __restrict__ valid) {
    int b = blockIdx.x;
    int L = blockIdx.y;
    int tw = 0, rem = L;
    while (rem >= NWORD - tw) { rem -= NWORD - tw; ++tw; }
    int tr = tw + rem;                   // tw <= tr: columns = earlier tile, rows = later
    __shared__ float4 jb[64];
    __shared__ float ja[64];
    int t = threadIdx.x;  // 64 threads
    const float4* bx = boxes + (size_t)b * RANKP;
    float4 v = bx[tw * 64 + t];
    jb[t] = v;
    ja[t] = (v.z - v.x) * (v.w - v.y);
    int i = tr * 64 + t;                 // this lane's row (later box)
    float4 bi = bx[i];
    float ai = (bi.z - bi.x) * (bi.w - bi.y);
    __syncthreads();
    u64 word = 0;
    for (int kk = 0; kk < 64; ++kk) {
        int j = tw * 64 + kk;
        float4 bj = jb[kk];
        float xx1 = fmaxf(bi.x, bj.x), yy1 = fmaxf(bi.y, bj.y);
        float xx2 = fminf(bi.z, bj.z), yy2 = fminf(bi.w, bj.w);
        float iw = fmaxf(xx2 - xx1, 0.f), ih = fmaxf(yy2 - yy1, 0.f);
        float inter = iw * ih;
        float iou = inter / (ai + ja[kk] - inter);   // NaN -> compare false
        if (j < i && iou > NMS_T) word |= 1ull << kk;
    }
    __builtin_nontemporal_store(word, &adj[((size_t)b * RANKP + i) * NWORD + tw]);
    if (word) atomicOr(&occ[(size_t)b * RANKP + i], 1u << tw);
    if (tw == tr) {
        bool ok = !((bi.z - bi.x < 1e-3f) || (bi.w - bi.y < 1e-3f));
        u64 bal = __ballot(ok);
        if (t == 0) valid[(size_t)b * NWORD + tr] = bal;
    }
}

// ---------------- Stage 6b+7: sparse greedy NMS + stable-partition output ----------------
// kept[i] = valid[i] && no kept j<i with IoU>T. Per 64-chunk: om = ballot(occ!=0);
// if om==0 (common): keptword = validword in O(1). Sparse rows resolved via readlane
// against prefetched first-adj-words (t1[], 32 regs, one latency) + rare global
// fallback for rows with >=2 occupied word-groups. No memory waits in the chain.
__global__ __launch_bounds__(64, 1) void k_nms(const u64* __restrict__ valid,
                                               const u64* __restrict__ adj,
                                               const uint32_t* __restrict__ occ,
                                               const float4* __restrict__ boxes,
                                               float4* __restrict__ out) {
    int b = blockIdx.x;
    int lane = threadIdx.x;             // 64
    const u64* AdjG = adj + (size_t)b * RANKP * NWORD;
    const uint32_t* OccG = occ + (size_t)b * RANKP;
    uint32_t o[NWORD];
#pragma unroll
    for (int g = 0; g < NWORD; ++g) o[g] = OccG[g * 64 + lane];
    u64 vw = (lane < 32) ? valid[(size_t)b * NWORD + lane] : 0ull;
    u64 t1[NWORD];
#pragma unroll
    for (int g = 0; g < NWORD; ++g) {
        uint32_t m = o[g];
        int w1 = m ? (int)__builtin_ctz(m) : 0;
        t1[g] = AdjG[(size_t)(g * 64 + lane) * NWORD + w1];
    }
    u64 kw = vw;
    int kcnt = 0;
    bool done = false;
#pragma unroll
    for (int c = 0; c < NWORD; ++c) {
        if (!done) {
            u64 om = __ballot(o[c] != 0);
            u64 vmask = readlane_u64(vw, c);
            u64 kc;
            if (om == 0ull) {
                kc = vmask;
            } else {
                kc = vmask & ~om;
                u64 mm = om;
                while (mm) {
                    int i = (int)__builtin_ctzll(mm); mm &= mm - 1;
                    uint32_t occv = __builtin_amdgcn_readlane(o[c], i);
                    bool suppressed = false;
                    uint32_t m2 = occv;
                    int w = (int)__builtin_ctz(m2); m2 &= m2 - 1;
                    u64 arow = readlane_u64(t1[c], i);
                    u64 ks = (w == c) ? kc : readlane_u64(kw, w);
                    if (arow & ks) suppressed = true;
                    while (m2 && !suppressed) {
                        w = (int)__builtin_ctz(m2); m2 &= m2 - 1;
                        u64 a2 = AdjG[(size_t)(c * 64 + i) * NWORD + w];
                        ks = (w == c) ? kc : readlane_u64(kw, w);
                        if (a2 & ks) suppressed = true;
                    }
                    if (((vmask >> i) & 1ull) && !suppressed) kc |= 1ull << i;
                }
            }
            if (lane == c) kw = kc;
            kcnt += (int)__popcll(kc);
            if (kcnt >= POST) done = true;
        }
    }
    // ---- epilogue: stable partition (kept first) -> top-1000 gather ----
    int tot = 0;
    for (int ww = 0; ww < NWORD; ++ww)
        tot += (int)__popcll(readlane_u64(kw, ww));
    u64 below = (1ull << lane) - 1ull;
    int kcum = 0, ucum = 0;
    for (int ww = 0; ww < NWORD; ++ww) {
        u64 kv = readlane_u64(kw, ww);
        int pc = (int)__popcll(kv);
        bool kp = (kv >> lane) & 1ull;
        int pos;
        if (kp) pos = kcum + (int)__popcll(kv & below);
        else    pos = tot + ucum + (int)__popcll((~kv) & below);
        if (pos < POST) out[(size_t)b * POST + pos] = boxes[(size_t)b * RANKP + ww * 64 + lane];
        kcum += pc;
        ucum += 64 - pc;
    }
}

extern "C" void kernel_launch(void* const* d_in, const int* in_sizes, int n_in,
                              void* d_out, int out_size, void* d_ws, size_t ws_size,
                              hipStream_t stream) {
    const float* anchors = (const float*)d_in[0];   // [N,4]
    const float* obj     = (const float*)d_in[1];   // [B,N]
    const float* deltas  = (const float*)d_in[2];   // [B,N,4]
    char* ws = (char*)d_ws;

    uint32_t* hist   = (uint32_t*)(ws + 0);        // 131072 (zeroed by k_zero)
    uint32_t* cnt    = (uint32_t*)(ws + 131072);   // 256    (zeroed by k_zero)
    uint32_t* occ    = (uint32_t*)(ws + 131328);   // 65536  (zeroed by k_rankdec) -> 196864
    u64*      cand   = (u64*)(ws + 196864);        // 262144 -> 459008
    float4*   boxes  = (float4*)(ws + 459008);     // 524288 -> 983296
    u64*      valid  = (u64*)(ws + 983296);        // 2048 -> 985344
    u64*      adj    = (u64*)(ws + 985344);        // 4194304 -> 5179648

    k_zero<<<(ZBYTES / 16 + 255) / 256, 256, 0, stream>>>((uint4*)ws);

    dim3 gscan(SCAN_BLOCKS, B);
    k_hist<<<gscan, 256, 0, stream>>>((const float4*)obj, hist);
    k_compact<<<gscan, 256, 0, stream>>>((const float4*)obj, hist, cnt, cand);
    dim3 grank(B, CAP / 64);
    k_rankdec<<<grank, 128, 0, stream>>>(cnt, cand, (const float4*)anchors,
                                         (const float4*)deltas, boxes, occ);
    dim3 gmask(B, NTRI);
    k_mask<<<gmask, 64, 0, stream>>>(boxes, adj, occ, valid);
    k_nms<<<B, 64, 0, stream>>>(valid, adj, occ, boxes, (float4*)d_out);
}

// Round 25
// 86.290 us; speedup vs baseline: 2.2984x; 1.2980x over previous
//
#include <hip/hip_runtime.h>
#include <stdint.h>

#define B 8
#define N 460800
#define NV4 115200          // N/4 float4 scores per image
#define PRE 2000
#define POST 1000
#define CAP 4096
#define NBIN 4096
#define RANKP 2048
#define NWORD 32
#define NMS_T 0.7f
#define XCLIP 4.135166556742356

#define SCAN_BLOCKS 45      // 45*256*10 = 115200  (few fat blocks: LDS-hist fixed costs)
#define SCAN_ITER 10
#define SCAN_STRIDE (SCAN_BLOCKS * 256)
#define NTRI (NWORD * (NWORD + 1) / 2)   // 528

typedef unsigned long long u64;

__device__ __forceinline__ uint32_t fkey(float f) {
    uint32_t u = __float_as_uint(f);
    return (u & 0x80000000u) ? ~u : (u | 0x80000000u);
}

__device__ __forceinline__ u64 readlane_u64(u64 v, int lane) {
    uint32_t lo = __builtin_amdgcn_readlane((uint32_t)v, lane);
    uint32_t hi = __builtin_amdgcn_readlane((uint32_t)(v >> 32), lane);
    return ((u64)hi << 32) | lo;
}

// ---------------- Stage 0: zero hist+cnt ----------------
#define ZBYTES 131328                     // hist (131072) + cnt (256)
__global__ __launch_bounds__(256) void k_zero(uint4* __restrict__ p) {
    int i = blockIdx.x * 256 + threadIdx.x;
    if (i < ZBYTES / 16) p[i] = make_uint4(0u, 0u, 0u, 0u);
}

// ---------------- Stage 1: per-image histogram of score keys (top 12 bits) ----------------
__global__ __launch_bounds__(256) void k_hist(const float4* __restrict__ obj4,
                                              uint32_t* __restrict__ hist) {
    __shared__ uint32_t lh[2][NBIN];   // 32 KiB, 2-way replicated to cut contention
    int b = blockIdx.y;
    for (int i = threadIdx.x; i < NBIN; i += 256) { lh[0][i] = 0; lh[1][i] = 0; }
    __syncthreads();
    const float4* s = obj4 + (size_t)b * NV4;
    int t0 = blockIdx.x * 256 + threadIdx.x;
    uint32_t* h = lh[threadIdx.x & 1];
    float4 v[SCAN_ITER];
#pragma unroll
    for (int k = 0; k < SCAN_ITER; ++k) v[k] = s[t0 + k * SCAN_STRIDE];
#pragma unroll
    for (int k = 0; k < SCAN_ITER; ++k) {
        atomicAdd(&h[fkey(v[k].x) >> 20], 1u);
        atomicAdd(&h[fkey(v[k].y) >> 20], 1u);
        atomicAdd(&h[fkey(v[k].z) >> 20], 1u);
        atomicAdd(&h[fkey(v[k].w) >> 20], 1u);
    }
    __syncthreads();
    uint32_t* gh = hist + (size_t)b * NBIN;
    for (int i = threadIdx.x; i < NBIN; i += 256) {
        uint32_t s2 = lh[0][i] + lh[1][i];
        if (s2) atomicAdd(&gh[i], s2);
    }
}

// ---------------- Stage 2+3 fused: wave 0 computes cutoff bin, then compact ------------
#define LBUF 2048
__global__ __launch_bounds__(256) void k_compact(const float4* __restrict__ obj4,
                                                 const uint32_t* __restrict__ hist,
                                                 uint32_t* __restrict__ cnt,
                                                 u64* __restrict__ cand) {
    __shared__ u64 buf[LBUF];          // 16 KiB
    __shared__ uint32_t lcnt, base, cutsh;
    int b = blockIdx.y;
    if (threadIdx.x == 0) lcnt = 0;
    if (threadIdx.x < 64) {
        int lane = threadIdx.x;
        const uint32_t* h = hist + (size_t)b * NBIN;
        uint32_t gs = 0;
        for (int t = 0; t < 64; ++t) gs += h[lane * 64 + t];
        uint32_t suf = gs;
        for (int d = 1; d < 64; d <<= 1) {
            uint32_t vv = __shfl_down(suf, d);
            if (lane + d < 64) suf += vv;
        }
        unsigned long long m = __ballot(suf >= PRE);
        int G = 63 - __clzll(m);
        uint32_t A = 0;
        if (G < 63) A = __shfl(suf, G + 1);
        uint32_t hv = h[G * 64 + lane];
        uint32_t suf2 = hv;
        for (int d = 1; d < 64; d <<= 1) {
            uint32_t vv = __shfl_down(suf2, d);
            if (lane + d < 64) suf2 += vv;
        }
        unsigned long long m2 = __ballot(A + suf2 >= PRE);
        int t2 = 63 - __clzll(m2);
        if (lane == 0) cutsh = (uint32_t)(G * 64 + t2);
    }
    __syncthreads();
    uint32_t cb = cutsh;
    const float4* s = obj4 + (size_t)b * NV4;
    int t0 = blockIdx.x * 256 + threadIdx.x;
    float4 v[SCAN_ITER];
#pragma unroll
    for (int k = 0; k < SCAN_ITER; ++k) v[k] = s[t0 + k * SCAN_STRIDE];
#pragma unroll
    for (int k = 0; k < SCAN_ITER; ++k) {
        int i4 = (t0 + k * SCAN_STRIDE) * 4;
        float fv[4] = {v[k].x, v[k].y, v[k].z, v[k].w};
#pragma unroll
        for (int c = 0; c < 4; ++c) {
            uint32_t key = fkey(fv[c]);
            if ((key >> 20) >= cb) {
                uint32_t p = atomicAdd(&lcnt, 1u);
                u64 e = ((u64)key << 32) | (uint32_t)(~(uint32_t)(i4 + c));
                if (p < LBUF) buf[p] = e;
                else {   // never expected; correctness fallback
                    uint32_t g = atomicAdd(&cnt[b], 1u);
                    if (g < CAP) cand[(size_t)b * CAP + g] = e;
                }
            }
        }
    }
    __syncthreads();
    uint32_t nb = lcnt < LBUF ? lcnt : LBUF;
    if (threadIdx.x == 0) base = atomicAdd(&cnt[b], nb);
    __syncthreads();
    uint32_t bs = base;
    for (uint32_t t = threadIdx.x; t < nb; t += 256) {
        uint32_t g = bs + t;
        if (g < CAP) cand[(size_t)b * CAP + g] = buf[t];
    }
}

// ---------------- Stage 4+5: counting-rank (2-wave split) + decode + occ-zero ----------------
// 128 threads: wave 0 scans j-groups [0,ng/2), wave 1 [ng/2,ng); partial ranks combined
// via LDS; wave 0 decodes + scatters + zeroes occ[rank] (bijective over [0,RANKP)).
__global__ __launch_bounds__(128) void k_rankdec(const uint32_t* __restrict__ cnt,
                                                 const u64* __restrict__ cand,
                                                 const float4* __restrict__ anchors,
                                                 const float4* __restrict__ deltas,
                                                 float4* __restrict__ boxes,
                                                 uint32_t* __restrict__ occ) {
    __shared__ uint32_t rpart[64];
    int b = blockIdx.x;
    int tid = threadIdx.x;
    int wid = tid >> 6, lane = tid & 63;
    int slot = blockIdx.y * 64 + lane;            // 0..4095
    uint32_t n = cnt[b]; if (n > CAP) n = CAP;
    const u64* C = cand + (size_t)b * CAP;
    u64 mykey = (slot < (int)n) ? C[slot] : 0ull;
    int r = 0;
    bool allpad = (blockIdx.y * 64 >= (int)n);    // whole block is pad rows
    if (!allpad) {
        int ng = ((int)n + 63) >> 6;
        int g0 = wid ? (ng >> 1) : 0;
        int g1 = wid ? ng : (ng >> 1);
        auto ld = [&](int g) -> u64 {
            int j = g * 64 + lane;
            int jc = j < (CAP - 1) ? j : (CAP - 1);
            u64 kv = C[jc];
            return (j < (int)n) ? kv : 0ull;      // 0 never counts (real keys have MSB set)
        };
        u64 kv0 = ld(g0), kv1 = ld(g0 + 1), kv2 = ld(g0 + 2);
        int r0 = 0, r1 = 0;
        for (int g = g0; g < g1; ++g) {
            u64 kvn = ld(g + 3);
#pragma unroll
            for (int t = 0; t < 64; t += 2) {
                u64 ka = readlane_u64(kv0, t);
                u64 kb = readlane_u64(kv0, t + 1);
                r0 += (ka > mykey) ? 1 : 0;
                r1 += (kb > mykey) ? 1 : 0;
            }
            kv0 = kv1; kv1 = kv2; kv2 = kvn;
        }
        r = r0 + r1;
    }
    if (wid == 1) rpart[lane] = (uint32_t)r;
    __syncthreads();
    if (wid == 0) {
        r += (int)rpart[lane];
        int rank = (slot < (int)n) ? r : slot;    // pads cover rows [n,2048) bijectively
        if (rank < RANKP) {
            float4 outb = make_float4(0.f, 0.f, 0.f, 0.f);
            if (slot < (int)n && rank < PRE) {
                uint32_t idx = ~(uint32_t)mykey;
                if (idx < N) {
                    float4 a = anchors[idx];
                    float4 d = deltas[(size_t)b * N + idx];
                    float w = a.z - a.x, h = a.w - a.y;
                    float cx = a.x + 0.5f * w, cy = a.y + 0.5f * h;
                    float dw = fminf(d.z, (float)XCLIP);
                    float dh = fminf(d.w, (float)XCLIP);
                    float pcx = d.x * w + cx, pcy = d.y * h + cy;
                    float pw = expf(dw) * w, ph = expf(dh) * h;
                    float x1 = pcx - 0.5f * pw, y1 = pcy - 0.5f * ph;
                    float x2 = pcx + 0.5f * pw, y2 = pcy + 0.5f * ph;
                    x1 = fminf(fmaxf(x1, 0.f), 1024.f);
                    y1 = fminf(fmaxf(y1, 0.f), 1024.f);
                    x2 = fminf(fmaxf(x2, 0.f), 1024.f);
                    y2 = fminf(fmaxf(y2, 0.f), 1024.f);
                    outb = make_float4(x1, y1, x2, y2);
                }
            }
            boxes[(size_t)b * RANKP + rank] = outb;
            occ[(size_t)b * RANKP + rank] = 0u;   // zero exactly once per row
        }
    }
}

// ---------------- Stage 6a: ADJACENCY bitmask + occupancy + valid ----------------
// adj[i][w] bit k: IoU(i, 64w+k) > T AND 64w+k < i (lower triangle; IoU numerically
// symmetric = exact transpose of suppression). occ[i] bit w iff adj[i][w]!=0 (rare;
// atomicOr onto k_rankdec-zeroed occ). Only words w <= i/64 WRITTEN; occ guards reads.
__global__ void k_mask(const float4* __restrict__ boxes, u64* __restrict__ adj,
                       uint32_t* __restrict__ occ, u64* __restrict__ valid) {
    int b = blockIdx.x;
    int L = blockIdx.y;
    int tw = 0, rem = L;
    while (rem >= NWORD - tw) { rem -= NWORD - tw; ++tw; }
    int tr = tw + rem;                   // tw <= tr: columns = earlier tile, rows = later
    __shared__ float4 jb[64];
    __shared__ float ja[64];
    int t = threadIdx.x;  // 64 threads
    const float4* bx = boxes + (size_t)b * RANKP;
    float4 v = bx[tw * 64 + t];
    jb[t] = v;
    ja[t] = (v.z - v.x) * (v.w - v.y);
    int i = tr * 64 + t;                 // this lane's row (later box)
    float4 bi = bx[i];
    float ai = (bi.z - bi.x) * (bi.w - bi.y);
    __syncthreads();
    u64 word = 0;
    for (int kk = 0; kk < 64; ++kk) {
        int j = tw * 64 + kk;
        float4 bj = jb[kk];
        float xx1 = fmaxf(bi.x, bj.x), yy1 = fmaxf(bi.y, bj.y);
        float xx2 = fminf(bi.z, bj.z), yy2 = fminf(bi.w, bj.w);
        float iw = fmaxf(xx2 - xx1, 0.f), ih = fmaxf(yy2 - yy1, 0.f);
        float inter = iw * ih;
        float iou = inter / (ai + ja[kk] - inter);   // NaN -> compare false
        if (j < i && iou > NMS_T) word |= 1ull << kk;
    }
    __builtin_nontemporal_store(word, &adj[((size_t)b * RANKP + i) * NWORD + tw]);
    if (word) atomicOr(&occ[(size_t)b * RANKP + i], 1u << tw);
    if (tw == tr) {
        bool ok = !((bi.z - bi.x < 1e-3f) || (bi.w - bi.y < 1e-3f));
        u64 bal = __ballot(ok);
        if (t == 0) valid[(size_t)b * NWORD + tr] = bal;
    }
}

// ---------------- Stage 6b+7: sparse greedy NMS + stable-partition output ----------------
// kept[i] = valid[i] && no kept j<i with IoU>T. Per 64-chunk: om = ballot(occ!=0);
// if om==0 (common): keptword = validword in O(1). Sparse rows resolved via readlane
// against prefetched first-adj-words (t1[], 32 regs, one latency) + rare global
// fallback for rows with >=2 occupied word-groups. No memory waits in the chain.
__global__ __launch_bounds__(64, 1) void k_nms(const u64* __restrict__ valid,
                                               const u64* __restrict__ adj,
                                               const uint32_t* __restrict__ occ,
                                               const float4* __restrict__ boxes,
                                               float4* __restrict__ out) {
    int b = blockIdx.x;
    int lane = threadIdx.x;             // 64
    const u64* AdjG = adj + (size_t)b * RANKP * NWORD;
    const uint32_t* OccG = occ + (size_t)b * RANKP;
    uint32_t o[NWORD];
#pragma unroll
    for (int g = 0; g < NWORD; ++g) o[g] = OccG[g * 64 + lane];
    u64 vw = (lane < 32) ? valid[(size_t)b * NWORD + lane] : 0ull;
    u64 t1[NWORD];
#pragma unroll
    for (int g = 0; g < NWORD; ++g) {
        uint32_t m = o[g];
        int w1 = m ? (int)__builtin_ctz(m) : 0;
        t1[g] = AdjG[(size_t)(g * 64 + lane) * NWORD + w1];
    }
    u64 kw = vw;
    int kcnt = 0;
    bool done = false;
#pragma unroll
    for (int c = 0; c < NWORD; ++c) {
        if (!done) {
            u64 om = __ballot(o[c] != 0);
            u64 vmask = readlane_u64(vw, c);
            u64 kc;
            if (om == 0ull) {
                kc = vmask;
            } else {
                kc = vmask & ~om;
                u64 mm = om;
                while (mm) {
                    int i = (int)__builtin_ctzll(mm); mm &= mm - 1;
                    uint32_t occv = __builtin_amdgcn_readlane(o[c], i);
                    bool suppressed = false;
                    uint32_t m2 = occv;
                    int w = (int)__builtin_ctz(m2); m2 &= m2 - 1;
                    u64 arow = readlane_u64(t1[c], i);
                    u64 ks = (w == c) ? kc : readlane_u64(kw, w);
                    if (arow & ks) suppressed = true;
                    while (m2 && !suppressed) {
                        w = (int)__builtin_ctz(m2); m2 &= m2 - 1;
                        u64 a2 = AdjG[(size_t)(c * 64 + i) * NWORD + w];
                        ks = (w == c) ? kc : readlane_u64(kw, w);
                        if (a2 & ks) suppressed = true;
                    }
                    if (((vmask >> i) & 1ull) && !suppressed) kc |= 1ull << i;
                }
            }
            if (lane == c) kw = kc;
            kcnt += (int)__popcll(kc);
            if (kcnt >= POST) done = true;
        }
    }
    // ---- epilogue: stable partition (kept first) -> top-1000 gather ----
    int tot = 0;
    for (int ww = 0; ww < NWORD; ++ww)
        tot += (int)__popcll(readlane_u64(kw, ww));
    u64 below = (1ull << lane) - 1ull;
    int kcum = 0, ucum = 0;
    for (int ww = 0; ww < NWORD; ++ww) {
        u64 kv = readlane_u64(kw, ww);
        int pc = (int)__popcll(kv);
        bool kp = (kv >> lane) & 1ull;
        int pos;
        if (kp) pos = kcum + (int)__popcll(kv & below);
        else    pos = tot + ucum + (int)__popcll((~kv) & below);
        if (pos < POST) out[(size_t)b * POST + pos] = boxes[(size_t)b * RANKP + ww * 64 + lane];
        kcum += pc;
        ucum += 64 - pc;
    }
}

extern "C" void kernel_launch(void* const* d_in, const int* in_sizes, int n_in,
                              void* d_out, int out_size, void* d_ws, size_t ws_size,
                              hipStream_t stream) {
    const float* anchors = (const float*)d_in[0];   // [N,4]
    const float* obj     = (const float*)d_in[1];   // [B,N]
    const float* deltas  = (const float*)d_in[2];   // [B,N,4]
    char* ws = (char*)d_ws;

    uint32_t* hist   = (uint32_t*)(ws + 0);        // 131072 (zeroed by k_zero)
    uint32_t* cnt    = (uint32_t*)(ws + 131072);   // 256    (zeroed by k_zero)
    uint32_t* occ    = (uint32_t*)(ws + 131328);   // 65536  (zeroed by k_rankdec) -> 196864
    u64*      cand   = (u64*)(ws + 196864);        // 262144 -> 459008
    float4*   boxes  = (float4*)(ws + 459008);     // 524288 -> 983296
    u64*      valid  = (u64*)(ws + 983296);        // 2048 -> 985344
    u64*      adj    = (u64*)(ws + 985344);        // 4194304 -> 5179648

    k_zero<<<(ZBYTES / 16 + 255) / 256, 256, 0, stream>>>((uint4*)ws);

    dim3 gscan(SCAN_BLOCKS, B);
    k_hist<<<gscan, 256, 0, stream>>>((const float4*)obj, hist);
    k_compact<<<gscan, 256, 0, stream>>>((const float4*)obj, hist, cnt, cand);
    dim3 grank(B, CAP / 64);
    k_rankdec<<<grank, 128, 0, stream>>>(cnt, cand, (const float4*)anchors,
                                         (const float4*)deltas, boxes, occ);
    dim3 gmask(B, NTRI);
    k_mask<<<gmask, 64, 0, stream>>>(boxes, adj, occ, valid);
    k_nms<<<B, 64, 0, stream>>>(valid, adj, occ, boxes, (float4*)d_out);
}